// Round 17
// baseline (235.042 us; speedup 1.0000x reference)
//
#include <hip/hip_runtime.h>
#include <math.h>

#define DIM    768
#define HEADS  12
#define HIDDEN 3072
#define SEQ    1024
#define NTOK   8192
#define QKVLD  2304

typedef __bf16 bf16_t;
typedef __bf16 bf16x4 __attribute__((ext_vector_type(4)));
typedef __bf16 bf16x8 __attribute__((ext_vector_type(8)));
typedef float  f32x4  __attribute__((ext_vector_type(4)));

union ABFrag { bf16x4 h[2]; bf16x8 v; };

__device__ __forceinline__ void gload16(const void* g, void* l) {
  __builtin_amdgcn_global_load_lds(
      (const __attribute__((address_space(1))) void*)g,
      (__attribute__((address_space(3))) void*)l, 16, 0, 0);
}

__device__ __forceinline__ f32x4 mfma16(bf16x8 a, bf16x8 b, f32x4 c) {
  return __builtin_amdgcn_mfma_f32_16x16x32_bf16(a, b, c, 0, 0, 0);
}

// BK=64 GEMM frag load: [rows][64] tile (128B rows), chunk lc stored at lc^(row&7).
__device__ __forceinline__ bf16x8 ldsfrag(const bf16_t* base, int row, int lc) {
  return *(const bf16x8*)(base + row * 64 + ((lc ^ (row & 7)) << 3));
}

// BK=32 GEMM frag load: [rows][32] tile (64B rows), chunk lc stored at
// lc ^ ((row>>1)&3). Bank audit: slot=(4(r&1)+pc)mod8 covers all 8 slots
// 2x across 16 rows -> 2-way (free, m136).
__device__ __forceinline__ bf16x8 ldsfrag32(const bf16_t* base, int row, int g) {
  return *(const bf16x8*)(base + row * 32 + ((g ^ ((row >> 1) & 3)) << 3));
}

// tanh-form GELU: 0.5x(1+tanh(sqrt(2/pi)(x+0.044715x^3))), max err vs exact ~3e-3.
__device__ __forceinline__ float gelu_f(float v) {
  float u = v * fmaf(v * v, 0.0356774081f, 0.7978845608f);
  u = fminf(u, 15.0f);
  float t = __builtin_amdgcn_exp2f(u * 2.8853900817779268f);  // e^{2u}
  return v * t * __builtin_amdgcn_rcpf(t + 1.0f);
}

// ---------------- LayerNorm: wave-per-row, fp32 in -> bf16 out ----------------
__global__ __launch_bounds__(256) void ln_kernel(
    const float* __restrict__ x, const float* __restrict__ gw,
    const float* __restrict__ bw, bf16_t* __restrict__ out) {
  const int row = blockIdx.x * 4 + (threadIdx.x >> 6);
  const int lane = threadIdx.x & 63;
  const float* xr = x + (size_t)row * DIM;
  f32x4 v[3];
  float s = 0.f, s2 = 0.f;
  #pragma unroll
  for (int i = 0; i < 3; ++i) {
    v[i] = *(const f32x4*)(xr + lane * 4 + i * 256);
    #pragma unroll
    for (int j = 0; j < 4; ++j) { s += v[i][j]; s2 += v[i][j] * v[i][j]; }
  }
  #pragma unroll
  for (int o = 32; o > 0; o >>= 1) {
    s += __shfl_xor(s, o);
    s2 += __shfl_xor(s2, o);
  }
  const float mu  = s * (1.0f / DIM);
  const float var = s2 * (1.0f / DIM) - mu * mu;
  const float rs  = rsqrtf(var + 1e-5f);
  bf16_t* orow = out + (size_t)row * DIM;
  #pragma unroll
  for (int i = 0; i < 3; ++i) {
    const int c = lane * 4 + i * 256;
    f32x4 gv = *(const f32x4*)(gw + c);
    f32x4 bv = *(const f32x4*)(bw + c);
    bf16x4 o4;
    #pragma unroll
    for (int j = 0; j < 4; ++j)
      o4[j] = (bf16_t)((v[i][j] - mu) * rs * gv[j] + bv[j]);
    *(bf16x4*)(orow + c) = o4;
  }
}

// ---- Batched weight transpose+convert: all 4 weights in ONE launch ----
struct WT4 {
  const float* W0; const float* W1; const float* W2; const float* W3;
  bf16_t* T0; bf16_t* T1; bf16_t* T2; bf16_t* T3;
};
__global__ __launch_bounds__(256) void wtrans4_kernel(WT4 p) {
  __shared__ float tile[32][33];
  const int bid = blockIdx.x;
  const float* W; bf16_t* Wt; int K, N, nx, lb;
  if (bid < 1728)      { W = p.W0; Wt = p.T0; K = 768;  N = 2304; nx = 72; lb = bid; }
  else if (bid < 2304) { W = p.W1; Wt = p.T1; K = 768;  N = 768;  nx = 24; lb = bid - 1728; }
  else if (bid < 4608) { W = p.W2; Wt = p.T2; K = 768;  N = 3072; nx = 96; lb = bid - 2304; }
  else                 { W = p.W3; Wt = p.T3; K = 3072; N = 768;  nx = 24; lb = bid - 4608; }
  const int bx = lb % nx, by = lb / nx;
  const int tx = threadIdx.x & 31, ty = threadIdx.x >> 5;
  const int n0 = bx * 32, k0 = by * 32;
  #pragma unroll
  for (int i = 0; i < 4; ++i)
    tile[ty + i * 8][tx] = W[(size_t)(k0 + ty + i * 8) * N + n0 + tx];
  __syncthreads();
  #pragma unroll
  for (int i = 0; i < 4; ++i)
    Wt[(size_t)(n0 + ty + i * 8) * K + k0 + tx] = (bf16_t)tile[tx][ty + i * 8];
}

// ------------- V transpose per head: qkv bf16 -> Vt[bh][64][SEQ] bf16 -------------
__global__ __launch_bounds__(256) void vtrans_kernel(
    const bf16_t* __restrict__ qkv, bf16_t* __restrict__ vt) {
  __shared__ bf16_t tile[64][68];  // tile[d][n]
  const int bh = blockIdx.y, b = bh / HEADS, h = bh % HEADS;
  const int n0 = blockIdx.x * 64;
  const int t = threadIdx.x;
  const int c = t & 15, r0 = t >> 4;
  const bf16_t* src = qkv + (size_t)(b * SEQ + n0) * QKVLD + 2 * DIM + h * 64;
  #pragma unroll
  for (int i = 0; i < 4; ++i) {
    const int n = r0 + i * 16;
    bf16x4 v4 = *(const bf16x4*)(src + (size_t)n * QKVLD + c * 4);
    #pragma unroll
    for (int j = 0; j < 4; ++j) tile[c * 4 + j][n] = v4[j];
  }
  __syncthreads();
  bf16_t* dst = vt + (size_t)bh * 64 * SEQ + n0;
  #pragma unroll
  for (int i = 0; i < 4; ++i) {
    const int d = r0 + i * 16;
    *(bf16x4*)(dst + (size_t)d * SEQ + c * 4) = *(const bf16x4*)(&tile[d][c * 4]);
  }
}

// ---- Double-buffered BK=32 GEMM (swizzled): BM=BN=128, 32 KB LDS ----
// Same LDS/occupancy footprint as the old single-buffered kernel (5 blocks/CU),
// same barrier rate (2 per 64-K), but loads issued a full K-step ahead.
template <int MODE>
__global__ __launch_bounds__(256) void gemm_db32(
    const bf16_t* __restrict__ A, const bf16_t* __restrict__ Bt,
    int N, int K,
    const float* __restrict__ bias, const float* __restrict__ res,
    void* __restrict__ outv, int gx) {
  __shared__ bf16_t sA[2][128 * 32];
  __shared__ bf16_t sB[2][128 * 32];
  const int tid = threadIdx.x;
  const int lane = tid & 63;
  const int wid = tid >> 6;
  const int g = lane >> 4, r16 = lane & 15;

  const int nwg = gridDim.x;
  const int cpx = nwg >> 3;
  const int sw = (blockIdx.x & 7) * cpx + (blockIdx.x >> 3);
  const int bx = sw % gx, by = sw / gx;
  const int row0 = by * 128, col0 = bx * 128;
  const int wr = (wid >> 1) * 64, wc = (wid & 1) * 64;

  // stage one 128x32 tile pair: 512 chunks each, pre-swizzled global source
  auto stage = [&](int p, int kt) {
    #pragma unroll
    for (int rnd = 0; rnd < 2; ++rnd) {
      const int c = rnd * 256 + tid;
      const int row = c >> 2, scp = (c & 3) ^ ((row >> 1) & 3);
      gload16(A + (size_t)(row0 + row) * K + (size_t)kt * 32 + scp * 8,
              &sA[p][c * 8]);
    }
    #pragma unroll
    for (int rnd = 0; rnd < 2; ++rnd) {
      const int c = rnd * 256 + tid;
      const int row = c >> 2, scp = (c & 3) ^ ((row >> 1) & 3);
      gload16(Bt + (size_t)(col0 + row) * K + (size_t)kt * 32 + scp * 8,
              &sB[p][c * 8]);
    }
  };

  f32x4 acc[4][4];
  #pragma unroll
  for (int m = 0; m < 4; ++m)
    #pragma unroll
    for (int n = 0; n < 4; ++n) acc[m][n] = f32x4{0.f, 0.f, 0.f, 0.f};

  const int kSteps = K >> 5;
  stage(0, 0);
  for (int kt = 0; kt < kSteps; ++kt) {
    const int cur = kt & 1;
    __syncthreads();  // buf[cur] loads (issued last iter) + prev reads complete
    if (kt + 1 < kSteps) stage(cur ^ 1, kt + 1);

    bf16x8 af[4], bfr[4];
    #pragma unroll
    for (int m = 0; m < 4; ++m) af[m] = ldsfrag32(&sA[cur][0], wr + m * 16 + r16, g);
    #pragma unroll
    for (int n = 0; n < 4; ++n) bfr[n] = ldsfrag32(&sB[cur][0], wc + n * 16 + r16, g);
    #pragma unroll
    for (int m = 0; m < 4; ++m)
      #pragma unroll
      for (int n = 0; n < 4; ++n)
        acc[m][n] = mfma16(af[m], bfr[n], acc[m][n]);
  }

  // Epilogue. C/D layout (HW-verified): col = lane&15, row = 4*(lane>>4)+reg.
  #pragma unroll
  for (int m = 0; m < 4; ++m) {
    const int rowb = row0 + wr + m * 16 + 4 * g;
    #pragma unroll
    for (int n = 0; n < 4; ++n) {
      const int col = col0 + wc + n * 16 + r16;
      const float bv = bias[col];
      #pragma unroll
      for (int r = 0; r < 4; ++r) {
        const size_t idx = (size_t)(rowb + r) * N + col;
        float v = acc[m][n][r] + bv;
        if (MODE == 0) {
          ((bf16_t*)outv)[idx] = (bf16_t)v;
        } else if (MODE == 1) {
          ((float*)outv)[idx] = v + res[idx];
        } else {
          ((bf16_t*)outv)[idx] = (bf16_t)gelu_f(v);
        }
      }
    }
  }
}

// ---- Double-buffered BK=64 GEMM (narrow-N latency regime): BM=128, BN=64 ----
template <int MODE, int BN>
__global__ __launch_bounds__(256) void gemm_db(
    const bf16_t* __restrict__ A, const bf16_t* __restrict__ Bt,
    int N, int K,
    const float* __restrict__ bias, const float* __restrict__ res,
    void* __restrict__ outv, int gx) {
  constexpr int WAVES_N = (BN == 128) ? 2 : 1;
  constexpr int WM = (BN == 128) ? 4 : 2;
  constexpr int WN = 4;
  __shared__ bf16_t sA[2][128 * 64];
  __shared__ bf16_t sB[2][BN * 64];
  const int tid = threadIdx.x;
  const int lane = tid & 63;
  const int wid = tid >> 6;
  const int g = lane >> 4, r16 = lane & 15;

  const int nwg = gridDim.x;
  const int cpx = nwg >> 3;
  const int sw = (blockIdx.x & 7) * cpx + (blockIdx.x >> 3);
  const int bx = sw % gx, by = sw / gx;
  const int row0 = by * 128, col0 = bx * BN;
  const int wr = (wid / WAVES_N) * (WM * 16);
  const int wc = (wid % WAVES_N) * (WN * 16);

  auto stage = [&](int p, int kt) {
    #pragma unroll
    for (int rnd = 0; rnd < 4; ++rnd) {
      const int c = rnd * 256 + tid;
      const int row = c >> 3, scp = (c & 7) ^ (row & 7);
      gload16(A + (size_t)(row0 + row) * K + (size_t)kt * 64 + scp * 8,
              &sA[p][c * 8]);
    }
    #pragma unroll
    for (int rnd = 0; rnd < BN / 32; ++rnd) {
      const int c = rnd * 256 + tid;
      const int row = c >> 3, scp = (c & 7) ^ (row & 7);
      gload16(Bt + (size_t)(col0 + row) * K + (size_t)kt * 64 + scp * 8,
              &sB[p][c * 8]);
    }
  };

  f32x4 acc[WM][WN];
  #pragma unroll
  for (int m = 0; m < WM; ++m)
    #pragma unroll
    for (int n = 0; n < WN; ++n) acc[m][n] = f32x4{0.f, 0.f, 0.f, 0.f};

  const int kSteps = K >> 6;
  stage(0, 0);
  for (int kt = 0; kt < kSteps; ++kt) {
    const int cur = kt & 1;
    __syncthreads();
    if (kt + 1 < kSteps) stage(cur ^ 1, kt + 1);

    bf16x8 af[WM][2], bfr[WN][2];
    #pragma unroll
    for (int m = 0; m < WM; ++m)
      #pragma unroll
      for (int kk = 0; kk < 2; ++kk)
        af[m][kk] = ldsfrag(&sA[cur][0], wr + m * 16 + r16, kk * 4 + g);
    #pragma unroll
    for (int n = 0; n < WN; ++n)
      #pragma unroll
      for (int kk = 0; kk < 2; ++kk)
        bfr[n][kk] = ldsfrag(&sB[cur][0], wc + n * 16 + r16, kk * 4 + g);
    #pragma unroll
    for (int kk = 0; kk < 2; ++kk)
      #pragma unroll
      for (int m = 0; m < WM; ++m)
        #pragma unroll
        for (int n = 0; n < WN; ++n)
          acc[m][n] = mfma16(af[m][kk], bfr[n][kk], acc[m][n]);
  }

  #pragma unroll
  for (int m = 0; m < WM; ++m) {
    const int rowb = row0 + wr + m * 16 + 4 * g;
    #pragma unroll
    for (int n = 0; n < WN; ++n) {
      const int col = col0 + wc + n * 16 + r16;
      const float bv = bias[col];
      #pragma unroll
      for (int r = 0; r < 4; ++r) {
        const size_t idx = (size_t)(rowb + r) * N + col;
        float v = acc[m][n][r] + bv;
        if (MODE == 0) {
          ((bf16_t*)outv)[idx] = (bf16_t)v;
        } else if (MODE == 1) {
          ((float*)outv)[idx] = v + res[idx];
        } else {
          ((bf16_t*)outv)[idx] = (bf16_t)gelu_f(v);
        }
      }
    }
  }
}

// ---- Flash attention: QBLK=128 (8 waves), KVBLK=64, fixed-shift exp2 softmax ----
__global__ __launch_bounds__(512) void attn_kernel(
    const bf16_t* __restrict__ qkv, const bf16_t* __restrict__ vt,
    bf16_t* __restrict__ o) {
  __shared__ bf16_t kbuf[2][64 * 64];
  __shared__ bf16_t vbuf[2][64 * 64];
  const int bh = blockIdx.x, b = bh / HEADS, h = bh % HEADS;
  const int q0 = blockIdx.y * 128;
  const int tid = threadIdx.x, lane = tid & 63, wid = tid >> 6;
  const int g = lane >> 4, r16 = lane & 15;

  const bf16_t* qptr = qkv + (size_t)b * SEQ * QKVLD + h * 64;
  const bf16_t* kptr = qptr + DIM;
  const bf16_t* vtp  = vt + (size_t)bh * 64 * SEQ;

  bf16x8 aq[2];
  {
    const bf16_t* qr = qptr + (size_t)(q0 + wid * 16 + r16) * QKVLD;
    aq[0] = *(const bf16x8*)(qr + 8 * g);
    aq[1] = *(const bf16x8*)(qr + 32 + 8 * g);
  }

  int koff[4][2];
  int voff[4][2][2];
  #pragma unroll
  for (int i = 0; i < 4; ++i) {
    const int row = i * 16 + r16, s = row & 7, rp = row * 64;
    #pragma unroll
    for (int e2 = 0; e2 < 2; ++e2) {
      koff[i][e2] = rp + (((4 * e2 + g) ^ s) << 3);
      const int o0 = e2 * 32 + 4 * g, o1 = o0 + 16;
      voff[i][e2][0] = rp + ((((o0 >> 3) ^ s) << 3) | (o0 & 7));
      voff[i][e2][1] = rp + ((((o1 >> 3) ^ s) << 3) | (o1 & 7));
    }
  }

  float lacc = 0.f;
  f32x4 acco[4];
  #pragma unroll
  for (int n = 0; n < 4; ++n) acco[n] = f32x4{0.f, 0.f, 0.f, 0.f};

  const int srow = tid >> 3, sscp = (tid & 7) ^ (srow & 7);
  const bf16_t* kSrc = kptr + (size_t)srow * QKVLD + sscp * 8;
  const bf16_t* vSrc = vtp + (size_t)srow * SEQ + sscp * 8;
  auto stage = [&](int buf, int kv0) {
    gload16(kSrc + (size_t)kv0 * QKVLD, &kbuf[buf][tid * 8]);
    gload16(vSrc + kv0, &vbuf[buf][tid * 8]);
  };

  const float C2 = 0.125f * 1.4426950408889634f;

  stage(0, 0);
  for (int it = 0; it < SEQ / 64; ++it) {
    const int cur = it & 1;
    __syncthreads();
    if (it + 1 < SEQ / 64) stage(cur ^ 1, (it + 1) * 64);
    const bf16_t* kb = kbuf[cur];
    const bf16_t* vb = vbuf[cur];

    f32x4 st[4];
    __builtin_amdgcn_s_setprio(1);
    #pragma unroll
    for (int t = 0; t < 4; ++t) {
      st[t] = f32x4{0.f, 0.f, 0.f, 0.f};
      st[t] = mfma16(*(const bf16x8*)(kb + koff[t][0]), aq[0], st[t]);
      st[t] = mfma16(*(const bf16x8*)(kb + koff[t][1]), aq[1], st[t]);
    }
    __builtin_amdgcn_s_setprio(0);

    float p[4][4];
    #pragma unroll
    for (int t = 0; t < 4; ++t)
      #pragma unroll
      for (int r = 0; r < 4; ++r) {
        float e = __builtin_amdgcn_exp2f(fmaf(st[t][r], C2, -16.0f));
        p[t][r] = e;
        lacc += e;
      }

    ABFrag pa0, pa1;
    #pragma unroll
    for (int r = 0; r < 4; ++r) {
      pa0.h[0][r] = (bf16_t)p[0][r];
      pa0.h[1][r] = (bf16_t)p[1][r];
      pa1.h[0][r] = (bf16_t)p[2][r];
      pa1.h[1][r] = (bf16_t)p[3][r];
    }

    __builtin_amdgcn_s_setprio(1);
    #pragma unroll
    for (int n = 0; n < 4; ++n) {
      ABFrag bv0, bv1;
      bv0.h[0] = *(const bf16x4*)(vb + voff[n][0][0]);
      bv0.h[1] = *(const bf16x4*)(vb + voff[n][0][1]);
      acco[n] = mfma16(pa0.v, bv0.v, acco[n]);
      bv1.h[0] = *(const bf16x4*)(vb + voff[n][1][0]);
      bv1.h[1] = *(const bf16x4*)(vb + voff[n][1][1]);
      acco[n] = mfma16(pa1.v, bv1.v, acco[n]);
    }
    __builtin_amdgcn_s_setprio(0);
  }

  float lt = lacc;
  lt += __shfl_xor(lt, 16);
  lt += __shfl_xor(lt, 32);
  float linv[4];
  #pragma unroll
  for (int r = 0; r < 4; ++r) linv[r] = 1.0f / __shfl(lt, 4 * g + r);
  bf16_t* op = o + (size_t)(b * SEQ + q0 + wid * 16 + 4 * g) * DIM + h * 64;
  #pragma unroll
  for (int n = 0; n < 4; ++n)
    #pragma unroll
    for (int r = 0; r < 4; ++r)
      op[(size_t)r * DIM + n * 16 + r16] = (bf16_t)(acco[n][r] * linv[r]);
}

extern "C" void kernel_launch(void* const* d_in, const int* in_sizes, int n_in,
                              void* d_out, int out_size, void* d_ws, size_t ws_size,
                              hipStream_t stream) {
  const float* x      = (const float*)d_in[0];
  const float* ln1_g  = (const float*)d_in[1];
  const float* ln1_b  = (const float*)d_in[2];
  const float* qkv_w  = (const float*)d_in[3];
  const float* qkv_b  = (const float*)d_in[4];
  const float* proj_w = (const float*)d_in[5];
  const float* proj_b = (const float*)d_in[6];
  const float* ln2_g  = (const float*)d_in[7];
  const float* ln2_b  = (const float*)d_in[8];
  const float* fc1_w  = (const float*)d_in[9];
  const float* fc1_b  = (const float*)d_in[10];
  const float* fc2_w  = (const float*)d_in[11];
  const float* fc2_b  = (const float*)d_in[12];
  float* out = (float*)d_out;

  char* ws = (char*)d_ws;
  size_t off = 0;
  auto alloc = [&](size_t bytes) -> void* {
    void* p = ws + off;
    off += (bytes + 255) & ~(size_t)255;
    return p;
  };
  bf16_t* wqkvT  = (bf16_t*)alloc((size_t)QKVLD * DIM * 2);
  bf16_t* wprojT = (bf16_t*)alloc((size_t)DIM * DIM * 2);
  bf16_t* wfc1T  = (bf16_t*)alloc((size_t)HIDDEN * DIM * 2);
  bf16_t* wfc2T  = (bf16_t*)alloc((size_t)DIM * HIDDEN * 2);
  bf16_t* buf1   = (bf16_t*)alloc((size_t)NTOK * DIM * 2);     // h1, then obf
  bf16_t* buf2   = (bf16_t*)alloc((size_t)NTOK * HIDDEN * 2);  // qkvbf, then h3
  bf16_t* buf3   = (bf16_t*)alloc((size_t)NTOK * DIM * 2);     // vt, then h2
  float*  x1     = (float*)alloc((size_t)NTOK * DIM * 4);

  bf16_t* h1 = buf1;     bf16_t* obf = buf1;
  bf16_t* qkvbf = buf2;  bf16_t* h3 = buf2;
  bf16_t* vt = buf3;     bf16_t* h2 = buf3;
  (void)in_sizes; (void)n_in; (void)out_size; (void)ws_size;

  WT4 wp;
  wp.W0 = qkv_w;  wp.T0 = wqkvT;
  wp.W1 = proj_w; wp.T1 = wprojT;
  wp.W2 = fc1_w;  wp.T2 = wfc1T;
  wp.W3 = fc2_w;  wp.T3 = wfc2T;
  wtrans4_kernel<<<6912, 256, 0, stream>>>(wp);

  ln_kernel<<<NTOK / 4, 256, 0, stream>>>(x, ln1_g, ln1_b, h1);
  gemm_db32<0><<<(QKVLD / 128) * (NTOK / 128), 256, 0, stream>>>(
      h1, wqkvT, QKVLD, DIM, qkv_b, nullptr, qkvbf, QKVLD / 128);
  vtrans_kernel<<<dim3(SEQ / 64, 8 * HEADS), 256, 0, stream>>>(qkvbf, vt);
  attn_kernel<<<dim3(8 * HEADS, SEQ / 128), 512, 0, stream>>>(qkvbf, vt, obf);
  gemm_db<1, 64><<<(DIM / 64) * (NTOK / 128), 256, 0, stream>>>(
      obf, wprojT, DIM, DIM, proj_b, x, x1, DIM / 64);
  ln_kernel<<<NTOK / 4, 256, 0, stream>>>(x1, ln2_g, ln2_b, h2);
  gemm_db32<2><<<(HIDDEN / 128) * (NTOK / 128), 256, 0, stream>>>(
      h2, wfc1T, HIDDEN, DIM, fc1_b, nullptr, h3, HIDDEN / 128);
  gemm_db<1, 64><<<(DIM / 64) * (NTOK / 128), 256, 0, stream>>>(
      h3, wfc2T, DIM, HIDDEN, fc2_b, x1, out, DIM / 64);
}

// Round 18
// 220.630 us; speedup vs baseline: 1.0653x; 1.0653x over previous
//
#include <hip/hip_runtime.h>
#include <math.h>

#define DIM    768
#define HEADS  12
#define HIDDEN 3072
#define SEQ    1024
#define NTOK   8192
#define QKVLD  2304

typedef __bf16 bf16_t;
typedef __bf16 bf16x4 __attribute__((ext_vector_type(4)));
typedef __bf16 bf16x8 __attribute__((ext_vector_type(8)));
typedef float  f32x4  __attribute__((ext_vector_type(4)));

union ABFrag { bf16x4 h[2]; bf16x8 v; };

__device__ __forceinline__ void gload16(const void* g, void* l) {
  __builtin_amdgcn_global_load_lds(
      (const __attribute__((address_space(1))) void*)g,
      (__attribute__((address_space(3))) void*)l, 16, 0, 0);
}

__device__ __forceinline__ f32x4 mfma16(bf16x8 a, bf16x8 b, f32x4 c) {
  return __builtin_amdgcn_mfma_f32_16x16x32_bf16(a, b, c, 0, 0, 0);
}

// BK=64 GEMM frag load: [rows][64] tile (128B rows), chunk lc stored at lc^(row&7).
__device__ __forceinline__ bf16x8 ldsfrag(const bf16_t* base, int row, int lc) {
  return *(const bf16x8*)(base + row * 64 + ((lc ^ (row & 7)) << 3));
}

// tanh-form GELU: 0.5x(1+tanh(sqrt(2/pi)(x+0.044715x^3))), max err vs exact ~3e-3.
__device__ __forceinline__ float gelu_f(float v) {
  float u = v * fmaf(v * v, 0.0356774081f, 0.7978845608f);
  u = fminf(u, 15.0f);
  float t = __builtin_amdgcn_exp2f(u * 2.8853900817779268f);  // e^{2u}
  return v * t * __builtin_amdgcn_rcpf(t + 1.0f);
}

// ---------------- LayerNorm: wave-per-row, fp32 in -> bf16 out ----------------
__global__ __launch_bounds__(256) void ln_kernel(
    const float* __restrict__ x, const float* __restrict__ gw,
    const float* __restrict__ bw, bf16_t* __restrict__ out) {
  const int row = blockIdx.x * 4 + (threadIdx.x >> 6);
  const int lane = threadIdx.x & 63;
  const float* xr = x + (size_t)row * DIM;
  f32x4 v[3];
  float s = 0.f, s2 = 0.f;
  #pragma unroll
  for (int i = 0; i < 3; ++i) {
    v[i] = *(const f32x4*)(xr + lane * 4 + i * 256);
    #pragma unroll
    for (int j = 0; j < 4; ++j) { s += v[i][j]; s2 += v[i][j] * v[i][j]; }
  }
  #pragma unroll
  for (int o = 32; o > 0; o >>= 1) {
    s += __shfl_xor(s, o);
    s2 += __shfl_xor(s2, o);
  }
  const float mu  = s * (1.0f / DIM);
  const float var = s2 * (1.0f / DIM) - mu * mu;
  const float rs  = rsqrtf(var + 1e-5f);
  bf16_t* orow = out + (size_t)row * DIM;
  #pragma unroll
  for (int i = 0; i < 3; ++i) {
    const int c = lane * 4 + i * 256;
    f32x4 gv = *(const f32x4*)(gw + c);
    f32x4 bv = *(const f32x4*)(bw + c);
    bf16x4 o4;
    #pragma unroll
    for (int j = 0; j < 4; ++j)
      o4[j] = (bf16_t)((v[i][j] - mu) * rs * gv[j] + bv[j]);
    *(bf16x4*)(orow + c) = o4;
  }
}

// ---- Batched weight transpose+convert: all 4 weights in ONE launch ----
struct WT4 {
  const float* W0; const float* W1; const float* W2; const float* W3;
  bf16_t* T0; bf16_t* T1; bf16_t* T2; bf16_t* T3;
};
__global__ __launch_bounds__(256) void wtrans4_kernel(WT4 p) {
  __shared__ float tile[32][33];
  const int bid = blockIdx.x;
  const float* W; bf16_t* Wt; int K, N, nx, lb;
  if (bid < 1728)      { W = p.W0; Wt = p.T0; K = 768;  N = 2304; nx = 72; lb = bid; }
  else if (bid < 2304) { W = p.W1; Wt = p.T1; K = 768;  N = 768;  nx = 24; lb = bid - 1728; }
  else if (bid < 4608) { W = p.W2; Wt = p.T2; K = 768;  N = 3072; nx = 96; lb = bid - 2304; }
  else                 { W = p.W3; Wt = p.T3; K = 3072; N = 768;  nx = 24; lb = bid - 4608; }
  const int bx = lb % nx, by = lb / nx;
  const int tx = threadIdx.x & 31, ty = threadIdx.x >> 5;
  const int n0 = bx * 32, k0 = by * 32;
  #pragma unroll
  for (int i = 0; i < 4; ++i)
    tile[ty + i * 8][tx] = W[(size_t)(k0 + ty + i * 8) * N + n0 + tx];
  __syncthreads();
  #pragma unroll
  for (int i = 0; i < 4; ++i)
    Wt[(size_t)(n0 + ty + i * 8) * K + k0 + tx] = (bf16_t)tile[tx][ty + i * 8];
}

// ------------- V transpose per head: qkv bf16 -> Vt[bh][64][SEQ] bf16 -------------
__global__ __launch_bounds__(256) void vtrans_kernel(
    const bf16_t* __restrict__ qkv, bf16_t* __restrict__ vt) {
  __shared__ bf16_t tile[64][68];  // tile[d][n]
  const int bh = blockIdx.y, b = bh / HEADS, h = bh % HEADS;
  const int n0 = blockIdx.x * 64;
  const int t = threadIdx.x;
  const int c = t & 15, r0 = t >> 4;
  const bf16_t* src = qkv + (size_t)(b * SEQ + n0) * QKVLD + 2 * DIM + h * 64;
  #pragma unroll
  for (int i = 0; i < 4; ++i) {
    const int n = r0 + i * 16;
    bf16x4 v4 = *(const bf16x4*)(src + (size_t)n * QKVLD + c * 4);
    #pragma unroll
    for (int j = 0; j < 4; ++j) tile[c * 4 + j][n] = v4[j];
  }
  __syncthreads();
  bf16_t* dst = vt + (size_t)bh * 64 * SEQ + n0;
  #pragma unroll
  for (int i = 0; i < 4; ++i) {
    const int d = r0 + i * 16;
    *(bf16x4*)(dst + (size_t)d * SEQ + c * 4) = *(const bf16x4*)(&tile[d][c * 4]);
  }
}

// ---- Single-buffered GEMM (occupancy regime, grid >= ~1000): BM=BN=128, BK=64 ----
// 32 KB LDS -> ~5 blocks/CU; inter-block TLP hides the staging drain (m114).
template <int MODE>
__global__ __launch_bounds__(256) void gemm_sb(
    const bf16_t* __restrict__ A, const bf16_t* __restrict__ Bt,
    int N, int K,
    const float* __restrict__ bias, const float* __restrict__ res,
    void* __restrict__ outv, int gx) {
  __shared__ bf16_t sA[128 * 64];
  __shared__ bf16_t sB[128 * 64];
  const int tid = threadIdx.x;
  const int lane = tid & 63;
  const int wid = tid >> 6;
  const int g = lane >> 4, r16 = lane & 15;

  const int nwg = gridDim.x;
  const int cpx = nwg >> 3;
  const int sw = (blockIdx.x & 7) * cpx + (blockIdx.x >> 3);
  const int bx = sw % gx, by = sw / gx;
  const int row0 = by * 128, col0 = bx * 128;
  const int wr = (wid >> 1) * 64, wc = (wid & 1) * 64;

  f32x4 acc[4][4];
  #pragma unroll
  for (int m = 0; m < 4; ++m)
    #pragma unroll
    for (int n = 0; n < 4; ++n) acc[m][n] = f32x4{0.f, 0.f, 0.f, 0.f};

  const int kSteps = K >> 6;
  for (int kt = 0; kt < kSteps; ++kt) {
    __syncthreads();
    #pragma unroll
    for (int rnd = 0; rnd < 4; ++rnd) {
      const int c = rnd * 256 + tid;
      const int row = c >> 3, scp = (c & 7) ^ (row & 7);
      gload16(A + (size_t)(row0 + row) * K + (size_t)kt * 64 + scp * 8, &sA[c * 8]);
    }
    #pragma unroll
    for (int rnd = 0; rnd < 4; ++rnd) {
      const int c = rnd * 256 + tid;
      const int row = c >> 3, scp = (c & 7) ^ (row & 7);
      gload16(Bt + (size_t)(col0 + row) * K + (size_t)kt * 64 + scp * 8, &sB[c * 8]);
    }
    __syncthreads();
    bf16x8 af[4][2], bfr[4][2];
    #pragma unroll
    for (int m = 0; m < 4; ++m)
      #pragma unroll
      for (int kk = 0; kk < 2; ++kk)
        af[m][kk] = ldsfrag(sA, wr + m * 16 + r16, kk * 4 + g);
    #pragma unroll
    for (int n = 0; n < 4; ++n)
      #pragma unroll
      for (int kk = 0; kk < 2; ++kk)
        bfr[n][kk] = ldsfrag(sB, wc + n * 16 + r16, kk * 4 + g);
    #pragma unroll
    for (int kk = 0; kk < 2; ++kk)
      #pragma unroll
      for (int m = 0; m < 4; ++m)
        #pragma unroll
        for (int n = 0; n < 4; ++n)
          acc[m][n] = mfma16(af[m][kk], bfr[n][kk], acc[m][n]);
  }

  #pragma unroll
  for (int m = 0; m < 4; ++m) {
    const int rowb = row0 + wr + m * 16 + 4 * g;
    #pragma unroll
    for (int n = 0; n < 4; ++n) {
      const int col = col0 + wc + n * 16 + r16;
      const float bv = bias[col];
      #pragma unroll
      for (int r = 0; r < 4; ++r) {
        const size_t idx = (size_t)(rowb + r) * N + col;
        float v = acc[m][n][r] + bv;
        if (MODE == 0) {
          ((bf16_t*)outv)[idx] = (bf16_t)v;
        } else if (MODE == 1) {
          ((float*)outv)[idx] = v + res[idx];
        } else {
          ((bf16_t*)outv)[idx] = (bf16_t)gelu_f(v);
        }
      }
    }
  }
}

// ---- Double-buffered BK=64 GEMM (narrow-N latency regime): BM=128, BN=64 ----
template <int MODE, int BN>
__global__ __launch_bounds__(256) void gemm_db(
    const bf16_t* __restrict__ A, const bf16_t* __restrict__ Bt,
    int N, int K,
    const float* __restrict__ bias, const float* __restrict__ res,
    void* __restrict__ outv, int gx) {
  constexpr int WAVES_N = (BN == 128) ? 2 : 1;
  constexpr int WM = (BN == 128) ? 4 : 2;
  constexpr int WN = 4;
  __shared__ bf16_t sA[2][128 * 64];
  __shared__ bf16_t sB[2][BN * 64];
  const int tid = threadIdx.x;
  const int lane = tid & 63;
  const int wid = tid >> 6;
  const int g = lane >> 4, r16 = lane & 15;

  const int nwg = gridDim.x;
  const int cpx = nwg >> 3;
  const int sw = (blockIdx.x & 7) * cpx + (blockIdx.x >> 3);
  const int bx = sw % gx, by = sw / gx;
  const int row0 = by * 128, col0 = bx * BN;
  const int wr = (wid / WAVES_N) * (WM * 16);
  const int wc = (wid % WAVES_N) * (WN * 16);

  auto stage = [&](int p, int kt) {
    #pragma unroll
    for (int rnd = 0; rnd < 4; ++rnd) {
      const int c = rnd * 256 + tid;
      const int row = c >> 3, scp = (c & 7) ^ (row & 7);
      gload16(A + (size_t)(row0 + row) * K + (size_t)kt * 64 + scp * 8,
              &sA[p][c * 8]);
    }
    #pragma unroll
    for (int rnd = 0; rnd < BN / 32; ++rnd) {
      const int c = rnd * 256 + tid;
      const int row = c >> 3, scp = (c & 7) ^ (row & 7);
      gload16(Bt + (size_t)(col0 + row) * K + (size_t)kt * 64 + scp * 8,
              &sB[p][c * 8]);
    }
  };

  f32x4 acc[WM][WN];
  #pragma unroll
  for (int m = 0; m < WM; ++m)
    #pragma unroll
    for (int n = 0; n < WN; ++n) acc[m][n] = f32x4{0.f, 0.f, 0.f, 0.f};

  const int kSteps = K >> 6;
  stage(0, 0);
  for (int kt = 0; kt < kSteps; ++kt) {
    const int cur = kt & 1;
    __syncthreads();
    if (kt + 1 < kSteps) stage(cur ^ 1, kt + 1);

    bf16x8 af[WM][2], bfr[WN][2];
    #pragma unroll
    for (int m = 0; m < WM; ++m)
      #pragma unroll
      for (int kk = 0; kk < 2; ++kk)
        af[m][kk] = ldsfrag(&sA[cur][0], wr + m * 16 + r16, kk * 4 + g);
    #pragma unroll
    for (int n = 0; n < WN; ++n)
      #pragma unroll
      for (int kk = 0; kk < 2; ++kk)
        bfr[n][kk] = ldsfrag(&sB[cur][0], wc + n * 16 + r16, kk * 4 + g);
    #pragma unroll
    for (int kk = 0; kk < 2; ++kk)
      #pragma unroll
      for (int m = 0; m < WM; ++m)
        #pragma unroll
        for (int n = 0; n < WN; ++n)
          acc[m][n] = mfma16(af[m][kk], bfr[n][kk], acc[m][n]);
  }

  #pragma unroll
  for (int m = 0; m < WM; ++m) {
    const int rowb = row0 + wr + m * 16 + 4 * g;
    #pragma unroll
    for (int n = 0; n < WN; ++n) {
      const int col = col0 + wc + n * 16 + r16;
      const float bv = bias[col];
      #pragma unroll
      for (int r = 0; r < 4; ++r) {
        const size_t idx = (size_t)(rowb + r) * N + col;
        float v = acc[m][n][r] + bv;
        if (MODE == 0) {
          ((bf16_t*)outv)[idx] = (bf16_t)v;
        } else if (MODE == 1) {
          ((float*)outv)[idx] = v + res[idx];
        } else {
          ((bf16_t*)outv)[idx] = (bf16_t)gelu_f(v);
        }
      }
    }
  }
}

// ---- Flash attention: QBLK=128 (8 waves), KVBLK=64, fixed-shift exp2 softmax ----
// Grid (x=bh, y=qtile): XCD = bh%8 -> all q-blocks of one (b,h) share an XCD.
// QK^T: contiguous k-map (single b128 per K-frag); PV: split map (P in regs).
// Softmax denominator via MFMA with a ones-operand: lsum4 = mfma(pa, ones)
// accumulates per-q row sums on the matrix pipe (row = 4g+r = q, all cols
// identical), replacing 16 VALU adds/iter + the end-of-loop shuffle reduce.
__global__ __launch_bounds__(512) void attn_kernel(
    const bf16_t* __restrict__ qkv, const bf16_t* __restrict__ vt,
    bf16_t* __restrict__ o) {
  __shared__ bf16_t kbuf[2][64 * 64];
  __shared__ bf16_t vbuf[2][64 * 64];
  const int bh = blockIdx.x, b = bh / HEADS, h = bh % HEADS;
  const int q0 = blockIdx.y * 128;
  const int tid = threadIdx.x, lane = tid & 63, wid = tid >> 6;
  const int g = lane >> 4, r16 = lane & 15;

  const bf16_t* qptr = qkv + (size_t)b * SEQ * QKVLD + h * 64;
  const bf16_t* kptr = qptr + DIM;
  const bf16_t* vtp  = vt + (size_t)bh * 64 * SEQ;

  bf16x8 aq[2];
  {
    const bf16_t* qr = qptr + (size_t)(q0 + wid * 16 + r16) * QKVLD;
    aq[0] = *(const bf16x8*)(qr + 8 * g);
    aq[1] = *(const bf16x8*)(qr + 32 + 8 * g);
  }

  bf16x8 ones;
  #pragma unroll
  for (int j = 0; j < 8; ++j) ones[j] = (bf16_t)1.0f;

  int koff[4][2];
  int voff[4][2][2];
  #pragma unroll
  for (int i = 0; i < 4; ++i) {
    const int row = i * 16 + r16, s = row & 7, rp = row * 64;
    #pragma unroll
    for (int e2 = 0; e2 < 2; ++e2) {
      koff[i][e2] = rp + (((4 * e2 + g) ^ s) << 3);
      const int o0 = e2 * 32 + 4 * g, o1 = o0 + 16;
      voff[i][e2][0] = rp + ((((o0 >> 3) ^ s) << 3) | (o0 & 7));
      voff[i][e2][1] = rp + ((((o1 >> 3) ^ s) << 3) | (o1 & 7));
    }
  }

  f32x4 lsum4 = f32x4{0.f, 0.f, 0.f, 0.f};
  f32x4 acco[4];
  #pragma unroll
  for (int n = 0; n < 4; ++n) acco[n] = f32x4{0.f, 0.f, 0.f, 0.f};

  const int srow = tid >> 3, sscp = (tid & 7) ^ (srow & 7);
  const bf16_t* kSrc = kptr + (size_t)srow * QKVLD + sscp * 8;
  const bf16_t* vSrc = vtp + (size_t)srow * SEQ + sscp * 8;
  auto stage = [&](int buf, int kv0) {
    gload16(kSrc + (size_t)kv0 * QKVLD, &kbuf[buf][tid * 8]);
    gload16(vSrc + kv0, &vbuf[buf][tid * 8]);
  };

  const float C2 = 0.125f * 1.4426950408889634f;

  stage(0, 0);
  for (int it = 0; it < SEQ / 64; ++it) {
    const int cur = it & 1;
    __syncthreads();
    if (it + 1 < SEQ / 64) stage(cur ^ 1, (it + 1) * 64);
    const bf16_t* kb = kbuf[cur];
    const bf16_t* vb = vbuf[cur];

    f32x4 st[4];
    __builtin_amdgcn_s_setprio(1);
    #pragma unroll
    for (int t = 0; t < 4; ++t) {
      st[t] = f32x4{0.f, 0.f, 0.f, 0.f};
      st[t] = mfma16(*(const bf16x8*)(kb + koff[t][0]), aq[0], st[t]);
      st[t] = mfma16(*(const bf16x8*)(kb + koff[t][1]), aq[1], st[t]);
    }
    __builtin_amdgcn_s_setprio(0);

    float p[4][4];
    #pragma unroll
    for (int t = 0; t < 4; ++t)
      #pragma unroll
      for (int r = 0; r < 4; ++r)
        p[t][r] = __builtin_amdgcn_exp2f(fmaf(st[t][r], C2, -16.0f));

    ABFrag pa0, pa1;
    #pragma unroll
    for (int r = 0; r < 4; ++r) {
      pa0.h[0][r] = (bf16_t)p[0][r];
      pa0.h[1][r] = (bf16_t)p[1][r];
      pa1.h[0][r] = (bf16_t)p[2][r];
      pa1.h[1][r] = (bf16_t)p[3][r];
    }

    __builtin_amdgcn_s_setprio(1);
    lsum4 = mfma16(pa0.v, ones, lsum4);
    #pragma unroll
    for (int n = 0; n < 4; ++n) {
      ABFrag bv0, bv1;
      bv0.h[0] = *(const bf16x4*)(vb + voff[n][0][0]);
      bv0.h[1] = *(const bf16x4*)(vb + voff[n][0][1]);
      acco[n] = mfma16(pa0.v, bv0.v, acco[n]);
      bv1.h[0] = *(const bf16x4*)(vb + voff[n][1][0]);
      bv1.h[1] = *(const bf16x4*)(vb + voff[n][1][1]);
      acco[n] = mfma16(pa1.v, bv1.v, acco[n]);
    }
    lsum4 = mfma16(pa1.v, ones, lsum4);
    __builtin_amdgcn_s_setprio(0);
  }

  // lsum4[r] = sum_kv P[q=4g+r][kv] (full contraction across all lanes' k-slots)
  float linv[4];
  #pragma unroll
  for (int r = 0; r < 4; ++r) linv[r] = 1.0f / lsum4[r];
  bf16_t* op = o + (size_t)(b * SEQ + q0 + wid * 16 + 4 * g) * DIM + h * 64;
  #pragma unroll
  for (int n = 0; n < 4; ++n)
    #pragma unroll
    for (int r = 0; r < 4; ++r)
      op[(size_t)r * DIM + n * 16 + r16] = (bf16_t)(acco[n][r] * linv[r]);
}

extern "C" void kernel_launch(void* const* d_in, const int* in_sizes, int n_in,
                              void* d_out, int out_size, void* d_ws, size_t ws_size,
                              hipStream_t stream) {
  const float* x      = (const float*)d_in[0];
  const float* ln1_g  = (const float*)d_in[1];
  const float* ln1_b  = (const float*)d_in[2];
  const float* qkv_w  = (const float*)d_in[3];
  const float* qkv_b  = (const float*)d_in[4];
  const float* proj_w = (const float*)d_in[5];
  const float* proj_b = (const float*)d_in[6];
  const float* ln2_g  = (const float*)d_in[7];
  const float* ln2_b  = (const float*)d_in[8];
  const float* fc1_w  = (const float*)d_in[9];
  const float* fc1_b  = (const float*)d_in[10];
  const float* fc2_w  = (const float*)d_in[11];
  const float* fc2_b  = (const float*)d_in[12];
  float* out = (float*)d_out;

  char* ws = (char*)d_ws;
  size_t off = 0;
  auto alloc = [&](size_t bytes) -> void* {
    void* p = ws + off;
    off += (bytes + 255) & ~(size_t)255;
    return p;
  };
  bf16_t* wqkvT  = (bf16_t*)alloc((size_t)QKVLD * DIM * 2);
  bf16_t* wprojT = (bf16_t*)alloc((size_t)DIM * DIM * 2);
  bf16_t* wfc1T  = (bf16_t*)alloc((size_t)HIDDEN * DIM * 2);
  bf16_t* wfc2T  = (bf16_t*)alloc((size_t)DIM * HIDDEN * 2);
  bf16_t* buf1   = (bf16_t*)alloc((size_t)NTOK * DIM * 2);     // h1, then obf
  bf16_t* buf2   = (bf16_t*)alloc((size_t)NTOK * HIDDEN * 2);  // qkvbf, then h3
  bf16_t* buf3   = (bf16_t*)alloc((size_t)NTOK * DIM * 2);     // vt, then h2
  float*  x1     = (float*)alloc((size_t)NTOK * DIM * 4);

  bf16_t* h1 = buf1;     bf16_t* obf = buf1;
  bf16_t* qkvbf = buf2;  bf16_t* h3 = buf2;
  bf16_t* vt = buf3;     bf16_t* h2 = buf3;
  (void)in_sizes; (void)n_in; (void)out_size; (void)ws_size;

  WT4 wp;
  wp.W0 = qkv_w;  wp.T0 = wqkvT;
  wp.W1 = proj_w; wp.T1 = wprojT;
  wp.W2 = fc1_w;  wp.T2 = wfc1T;
  wp.W3 = fc2_w;  wp.T3 = wfc2T;
  wtrans4_kernel<<<6912, 256, 0, stream>>>(wp);

  ln_kernel<<<NTOK / 4, 256, 0, stream>>>(x, ln1_g, ln1_b, h1);
  gemm_sb<0><<<(QKVLD / 128) * (NTOK / 128), 256, 0, stream>>>(
      h1, wqkvT, QKVLD, DIM, qkv_b, nullptr, qkvbf, QKVLD / 128);
  vtrans_kernel<<<dim3(SEQ / 64, 8 * HEADS), 256, 0, stream>>>(qkvbf, vt);
  attn_kernel<<<dim3(8 * HEADS, SEQ / 128), 512, 0, stream>>>(qkvbf, vt, obf);
  gemm_db<1, 64><<<(DIM / 64) * (NTOK / 128), 256, 0, stream>>>(
      obf, wprojT, DIM, DIM, proj_b, x, x1, DIM / 64);
  ln_kernel<<<NTOK / 4, 256, 0, stream>>>(x1, ln2_g, ln2_b, h2);
  gemm_sb<2><<<(HIDDEN / 128) * (NTOK / 128), 256, 0, stream>>>(
      h2, wfc1T, HIDDEN, DIM, fc1_b, nullptr, h3, HIDDEN / 128);
  gemm_db<1, 64><<<(DIM / 64) * (NTOK / 128), 256, 0, stream>>>(
      h3, wfc2T, DIM, HIDDEN, fc2_b, x1, out, DIM / 64);
}